// Round 12
// baseline (2848.905 us; speedup 1.0000x reference)
//
#include <hip/hip_runtime.h>
#include <hip/hip_bf16.h>

#define DI __device__ __forceinline__

typedef short bf16x8 __attribute__((ext_vector_type(8)));
typedef float f32x4 __attribute__((ext_vector_type(4)));
typedef int   i32x4 __attribute__((ext_vector_type(4)));
typedef unsigned short u16;

constexpr int TT = 512, BB = 256, HH = 256, VV = 128;

DI u16 f2b(float f){ __hip_bfloat16 h = __float2bfloat16(f); u16 r; __builtin_memcpy(&r,&h,2); return r; }
DI float b2f(u16 v){ unsigned u = ((unsigned)v)<<16; float f; __builtin_memcpy(&f,&u,4); return f; }
DI f32x4 mfma16(bf16x8 a, bf16x8 b, f32x4 c){ return __builtin_amdgcn_mfma_f32_16x16x32_bf16(a,b,c,0,0,0); }

// ---------------------------------------------------------------------------
// pack W [N][K] f32 -> B-fragment layout: frag(ntg,kt,lane)[j] =
//   bf16( W[ntg*16 + (lane&15)][kt*32 + (lane>>4)*8 + j] ), linear at tid*8.
// ---------------------------------------------------------------------------
__global__ void pack_b(const float* __restrict__ W, u16* __restrict__ o, int N, int K){
  const int tid = blockIdx.x*256 + threadIdx.x;
  const int KT = K >> 5;
  const int total = (N>>4)*KT*64;
  if (tid >= total) return;
  const int lane = tid & 63;
  const int rest = tid >> 6;
  const int kt  = rest % KT;
  const int ntg = rest / KT;
  const int n  = (ntg<<4) + (lane&15);
  const int k0 = (kt<<5) + ((lane>>4)<<3);
  const float* s = W + (size_t)n*K + k0;
  bf16x8 pv;
#pragma unroll
  for (int j=0;j<8;++j) pv[j] = (short)f2b(s[j]);
  *(bf16x8*)(o + (size_t)tid*8) = pv;
}

__global__ void bias_sum(const float* a0,const float* b0,float* o0,
                         const float* a1,const float* b1,float* o1){
  int i = blockIdx.x*256 + threadIdx.x;
  if (i < 1024) o0[i] = a0[i] + b0[i];
  else if (i < 2048) { int j=i-1024; o1[j] = a1[j] + b1[j]; }
}

// ---------------------------------------------------------------------------
// GEMM body -> quadrant-split permuted bf16 xg, coalesced epilogue.
// xg u16 index: ((((t*4 + q4)*16 + bg)*8 + wr)*64 + l)*8 + p*4 + i
// ---------------------------------------------------------------------------
template<int KT, bool AF32>
DI void gemm_body(char* smem, const void* __restrict__ A_,
                  const u16* __restrict__ Bp, const float* __restrict__ bias,
                  u16* __restrict__ xgp, int lda, int bx, int by)
{
  constexpr int NT = 8;
  const int tid = threadIdx.x;
  const int l = tid & 63, w = tid >> 6;
  const int l15 = l & 15, g4 = l >> 4;
  const int mw = w >> 1, nw = w & 1;
  const int col0 = bx * 256;
  const int row0 = by * 64;

  { // stage packed-B slice (contiguous) into LDS
    const int n16 = 2*NT*KT*64;
    const i32x4* src = (const i32x4*)(Bp + (size_t)(col0>>4)*KT*64*8);
    i32x4* dst = (i32x4*)smem;
    for (int i=tid; i<n16; i+=512) dst[i] = src[i];
  }
  __syncthreads();

  f32x4 acc[NT];
#pragma unroll
  for (int nt=0; nt<NT; ++nt) acc[nt] = (f32x4){0.f,0.f,0.f,0.f};

  const int rowA = row0 + mw*16 + l15;
#pragma unroll
  for (int kt=0; kt<KT; ++kt){
    bf16x8 a;
    const int k0 = kt*32 + g4*8;
    if constexpr (AF32){
      const float* ap = (const float*)A_ + (size_t)rowA*lda + k0;
      const f32x4 x0 = *(const f32x4*)ap;
      const f32x4 x1 = *(const f32x4*)(ap+4);
#pragma unroll
      for (int j=0;j<4;++j){ a[j] = (short)f2b(x0[j]); a[j+4] = (short)f2b(x1[j]); }
    } else {
      a = *(const bf16x8*)((const u16*)A_ + (size_t)rowA*lda + k0);
    }
#pragma unroll
    for (int nt=0; nt<NT; ++nt){
      const bf16x8 b = *(const bf16x8*)(smem + (size_t)(((nw*NT+nt)*KT + kt)*64 + l)*16);
      acc[nt] = mfma16(a,b,acc[nt]);
    }
  }

  // coalesced permuted epilogue: one 16B store per wr
  const int t  = row0 >> 8;
  const int bg = ((row0 & 255) >> 4) + mw;
#pragma unroll
  for (int j=0;j<4;++j){
    bf16x8 pk;
#pragma unroll
    for (int p=0;p<2;++p){
      const int nt = 2*j + p;
      const float bv = bias[col0 + (nw*8+nt)*16 + l15];
#pragma unroll
      for (int i=0;i<4;++i) pk[p*4+i] = (short)f2b(acc[nt][i] + bv);
    }
    const int wr = nw*4 + j;
    *(bf16x8*)(xgp + ((((size_t)(t*4 + bx)*16 + bg)*8 + wr)*64 + l)*8) = pk;
  }
}

__global__ __launch_bounds__(512,2) void gemm_perm0(const float* A, const u16* Bp,
    const float* bias, u16* xgp){
  __shared__ char smem[65536];
  gemm_body<4,true>(smem, A, Bp, bias, xgp, VV, blockIdx.x, blockIdx.y);
}

// ---------------------------------------------------------------------------
// FC body: C[64 x 128] f32 = A[64 x 256] bf16 @ WfcP + bfc, in-place over A
// rows (pre-epilogue barrier). KT=8, NT=4 (one col block). LDS 65536.
// ---------------------------------------------------------------------------
DI void fc_body(char* smem, const u16* __restrict__ A_,
                const u16* __restrict__ Bp, const float* __restrict__ bias,
                float* __restrict__ C_, int by)
{
  constexpr int KT = 8, NT = 4;
  const int tid = threadIdx.x;
  const int l = tid & 63, w = tid >> 6;
  const int l15 = l & 15, g4 = l >> 4;
  const int mw = w >> 1, nw = w & 1;
  const int row0 = by * 64;

  {
    const int n16 = 2*NT*KT*64;
    const i32x4* src = (const i32x4*)Bp;
    i32x4* dst = (i32x4*)smem;
    for (int i=tid; i<n16; i+=512) dst[i] = src[i];
  }
  __syncthreads();

  f32x4 acc[NT];
#pragma unroll
  for (int nt=0; nt<NT; ++nt) acc[nt] = (f32x4){0.f,0.f,0.f,0.f};

  const int rowA = row0 + mw*16 + l15;
#pragma unroll
  for (int kt=0; kt<KT; ++kt){
    const bf16x8 a = *(const bf16x8*)(A_ + (size_t)rowA*HH + kt*32 + g4*8);
#pragma unroll
    for (int nt=0; nt<NT; ++nt){
      const bf16x8 b = *(const bf16x8*)(smem + (size_t)(((nw*NT+nt)*KT + kt)*64 + l)*16);
      acc[nt] = mfma16(a,b,acc[nt]);
    }
  }

  __syncthreads();   // drain all A-loads in block before in-place C-stores

#pragma unroll
  for (int nt=0; nt<NT; ++nt){
    const int col = (nw*NT+nt)*16 + l15;
    const float bv = bias[col];
#pragma unroll
    for (int i=0;i<4;++i)
      C_[(size_t)(row0 + mw*16 + 4*g4 + i)*VV + col] = acc[nt][i] + bv;
  }
}

// ---------------------------------------------------------------------------
// Recurrent chunk body — BARRIER-FREE dataflow version.
// Wave w owns hidden units [32w,32w+32). W: i,f resident regs; o in LDS;
// g streamed from L2 (R9 layout). h TRIPLE-buffered in LDS (skew<2 proven).
// Per-step sync: wave w's MFMA over h-tile kt waits on flg[kt] >= t-1
// (acquire, LDS scope); after nonlin h-writes, release-store flg[w]=t.
// kt order rotated per wave (own tile first): kt=(w+j)&7; W storage rotated
// by j so all register indices are compile-time (rule #20). lgkm-only sync:
// no vmcnt drain anywhere in the step loop.
// ---------------------------------------------------------------------------
DI void rec_body(char* smW, char* bA, char* bB, char* bC, int* flg,
    const u16* __restrict__ xg, const u16* __restrict__ Whhp,
    const float* h_in, const float* c_in, u16* __restrict__ y,
    float* hout, float* cout, int bg, int nsteps)
{
  const int tid = threadIdx.x;
  const int w0 = tid >> 6, l = tid & 63;
  const int l15 = l & 15, g4 = l >> 4;
  const int b0 = bg * 16;

  if (tid < 8) flg[tid] = -1;

  const u16* xt = xg + ((size_t)(bg*8 + w0)*64 + l)*8;   // +262144 u16/step
  u16* yp = y + (size_t)(b0 + 4*g4)*256 + 32*w0 + l15;   // +65536 u16/step

  bf16x8 xsv[4];
#pragma unroll
  for (int q=0;q<4;++q) xsv[q] = *(const bf16x8*)(xt + q*65536);

  // resident W (i,f), ROTATED: Wr[nt][j] = frag for kt=(w0+j)&7
  bf16x8 Wr[4][8];
#pragma unroll
  for (int nt=0; nt<4; ++nt){
    const int ntg = ((nt>>1)<<4) + (w0<<1) + (nt&1);
#pragma unroll
    for (int j=0; j<8; ++j){
      const int kt = (w0 + j) & 7;
      Wr[nt][j] = *(const bf16x8*)(Whhp + (((size_t)ntg*8 + kt)*64 + l)*8);
    }
  }
  // o tiles -> LDS in frag layout (read back with runtime kt addresses)
#pragma unroll
  for (int ntl=0; ntl<2; ++ntl){
    const int ntg = 48 + (w0<<1) + ntl;
#pragma unroll
    for (int kt=0; kt<8; ++kt){
      bf16x8 v = *(const bf16x8*)(Whhp + (((size_t)ntg*8 + kt)*64 + l)*8);
      *(bf16x8*)(smW + (size_t)((w0*16 + ntl*8 + kt)*64 + l)*16) = v;
    }
  }
  // g streams (rotated): base pointers; persistent j=0,1 frags loaded once
  const u16* wg0 = Whhp + (((size_t)(32 + 2*w0)*8)*64 + l)*8;
  const u16* wg1 = Whhp + (((size_t)(33 + 2*w0)*8)*64 + l)*8;
  const bf16x8 p00 = *(const bf16x8*)(wg0 + (size_t)( w0      & 7)*512);
  const bf16x8 p01 = *(const bf16x8*)(wg0 + (size_t)((w0 + 1) & 7)*512);
  const bf16x8 p10 = *(const bf16x8*)(wg1 + (size_t)( w0      & 7)*512);
  const bf16x8 p11 = *(const bf16x8*)(wg1 + (size_t)((w0 + 1) & 7)*512);

  float c[2][4];
#pragma unroll
  for (int hf=0; hf<2; ++hf)
#pragma unroll
    for (int i=0;i<4;++i){
      const int b  = 4*g4 + i;
      const int jh = 32*w0 + 16*hf + l15;
      c[hf][i] = c_in[(size_t)(b0+b)*256 + jh];
      *(u16*)(bA + (size_t)b*528 + 2*jh) = f2b(h_in[(size_t)(b0+b)*256 + jh]);
    }
  __syncthreads();   // h0 + o-W + flags visible; ONLY barrier in the kernel

  char* br = bA; char* bw = bB; char* bn = bC;

  for (int t = 0; t < nsteps; ++t) {
    bf16x8 gA[8], gB[8];
    gA[0]=p00; gA[1]=p01; gB[0]=p10; gB[1]=p11;
    f32x4 acc[8];

#pragma unroll
    for (int j=0; j<8; ++j){
      const int kt = (w0 + j) & 7;
      if (j){   // wait: producer wave kt finished step t-1 (wrote h_t tile kt)
        int bail = 0;
        for (;;){
          const int f = __hip_atomic_load(&flg[kt], __ATOMIC_ACQUIRE,
                                          __HIP_MEMORY_SCOPE_WORKGROUP);
          if (f >= t-1 || ++bail > (1<<22)) break;
          __builtin_amdgcn_s_sleep(1);
        }
      }
      const bf16x8 a = *(const bf16x8*)(br + (size_t)l15*528 + kt*64 + g4*16);
      if (j == 0){
        // C-inputs = staged xg(t)
        f32x4 xv[8];
#pragma unroll
        for (int nt=0; nt<4; ++nt)
#pragma unroll
          for (int i=0;i<4;++i) xv[nt][i] = b2f((u16)xsv[nt>>1][(nt&1)*4+i]);
#pragma unroll
        for (int i=0;i<4;++i){
          xv[4][i] = b2f((u16)xsv[2][i]);   xv[5][i] = b2f((u16)xsv[2][4+i]);
          xv[6][i] = b2f((u16)xsv[3][i]);   xv[7][i] = b2f((u16)xsv[3][4+i]);
        }
#pragma unroll
        for (int nt=0; nt<4; ++nt) acc[nt] = mfma16(a, Wr[nt][0], xv[nt]);
        acc[4] = mfma16(a, gA[0], xv[4]);
        acc[5] = mfma16(a, gB[0], xv[5]);
        {
          const bf16x8 wl0 = *(const bf16x8*)(smW + (size_t)((w0*16 +      kt)*64 + l)*16);
          const bf16x8 wl1 = *(const bf16x8*)(smW + (size_t)((w0*16 + 8 +  kt)*64 + l)*16);
          acc[6] = mfma16(a, wl0, xv[6]);
          acc[7] = mfma16(a, wl1, xv[7]);
        }
        xt += 262144;                 // prefetch next step's xg (slack-padded)
#pragma unroll
        for (int q=0;q<4;++q) xsv[q] = *(const bf16x8*)(xt + q*65536);
      } else {
#pragma unroll
        for (int nt=0; nt<4; ++nt) acc[nt] = mfma16(a, Wr[nt][j], acc[nt]);
        acc[4] = mfma16(a, gA[j], acc[4]);
        acc[5] = mfma16(a, gB[j], acc[5]);
        const bf16x8 wl0 = *(const bf16x8*)(smW + (size_t)((w0*16 +      kt)*64 + l)*16);
        const bf16x8 wl1 = *(const bf16x8*)(smW + (size_t)((w0*16 + 8 +  kt)*64 + l)*16);
        acc[6] = mfma16(a, wl0, acc[6]);
        acc[7] = mfma16(a, wl1, acc[7]);
      }
      if (j < 6){                     // stream g frag j+2, 2-ahead
        gA[j+2] = *(const bf16x8*)(wg0 + (size_t)((w0 + j + 2) & 7)*512);
        gB[j+2] = *(const bf16x8*)(wg1 + (size_t)((w0 + j + 2) & 7)*512);
      }
    }

    // nonlinearity + state update (fused reciprocals, exact algebra)
    u16 hb[8];
#pragma unroll
    for (int hf=0; hf<2; ++hf)
#pragma unroll
      for (int i=0;i<4;++i){
        const float xi = acc[0+hf][i];
        const float xf = acc[2+hf][i];
        const float xG = acc[4+hf][i];
        const float xo = acc[6+hf][i];
        const float ai = __builtin_amdgcn_exp2f(-1.4426950408889634f*xi);
        const float af = __builtin_amdgcn_exp2f(-1.4426950408889634f*xf);
        const float eg = __builtin_amdgcn_exp2f(-2.8853900817779268f*xG);
        const float rig = __builtin_amdgcn_rcpf((1.0f+ai)*(1.0f+eg));
        const float rf  = __builtin_amdgcn_rcpf(1.0f+af);
        const float cc  = c[hf][i]*rf + (1.0f-eg)*rig;
        c[hf][i] = cc;
        const float ao = __builtin_amdgcn_exp2f(-1.4426950408889634f*xo);
        const float dc = __builtin_amdgcn_exp2f(-2.8853900817779268f*cc);
        const float roc = __builtin_amdgcn_rcpf((1.0f+ao)*(1.0f+dc));
        const float hh  = (1.0f-dc)*roc;
        hb[hf*4+i] = f2b(hh);
        *(u16*)(bw + (size_t)(4*g4+i)*528 + 2*(32*w0 + 16*hf + l15)) = hb[hf*4+i];
      }

    // release: h-tile w0 for step t+1 is visible (lgkm-only drain)
    __hip_atomic_store(&flg[w0], t, __ATOMIC_RELEASE, __HIP_MEMORY_SCOPE_WORKGROUP);

    // y-stores after the release (off other waves' critical path)
#pragma unroll
    for (int hf=0; hf<2; ++hf)
#pragma unroll
      for (int i=0;i<4;++i)
        yp[(size_t)i*256 + hf*16] = hb[hf*4+i];
    yp += 65536;

    { char* t0 = br; br = bw; bw = bn; bn = t0; }   // rotate triple buffer
  }

  // tail: final state write-back (h_nsteps in br; own tile, own writes)
#pragma unroll
  for (int hf=0; hf<2; ++hf)
#pragma unroll
    for (int i=0;i<4;++i){
      const int b  = 4*g4 + i;
      const int jh = 32*w0 + 16*hf + l15;
      hout[(size_t)(b0+b)*256 + jh] = b2f(*(u16*)(br + (size_t)b*528 + 2*jh));
      cout[(size_t)(b0+b)*256 + jh] = c[hf][i];
    }
}

// ---------------------------------------------------------------------------
// Mega dispatch d — cross-dispatch independent roles (kernel-boundary
// coherence; zero global atomics):
//   blocks 0-15 : R0(d), 16-31: R1(d-2), 32+: G0(d+1), G1(d-1), FC(d-3)
// Grid 256 x 512thr, LDS ~153K -> 1 block/CU.
// ---------------------------------------------------------------------------
__global__ __launch_bounds__(512,2) void mega(
    int hasR0, int hasR1, int hasG0, int hasG1, int hasFC, int nsteps,
    const u16* __restrict__ xg0r, const float* hinA, const float* cinA,
    u16* y0wr, float* houtA, float* coutA,
    const u16* __restrict__ xg1r, const float* hinB, const float* cinB,
    u16* y1wr, float* houtB, float* coutB,
    const float* __restrict__ xG0, u16* __restrict__ xg0w,
    const u16* __restrict__ y0rd, u16* __restrict__ xg1w,
    const u16* __restrict__ y1fc, float* __restrict__ outfc,
    const u16* __restrict__ wih0p, const float* __restrict__ bias0,
    const u16* __restrict__ wih1p, const float* __restrict__ bias1,
    const u16* __restrict__ whh0p, const u16* __restrict__ whh1p,
    const u16* __restrict__ wfcp,  const float* __restrict__ bfc)
{
  __shared__ char smem[156416];   // o-W 131072 + 3 x 8448 h bufs
  __shared__ int  flgS[8];        // per-wave dataflow flags (LDS addrspace)
  const int bid = (int)blockIdx.x;
  const int ntG = nsteps * 16;

  if (bid < 16){
    if (hasR0)
      rec_body(smem, smem+131072, smem+139520, smem+147968, flgS, xg0r, whh0p,
               hinA, cinA, y0wr, houtA, coutA, bid, nsteps);
  } else if (bid < 32){
    if (hasR1)
      rec_body(smem, smem+131072, smem+139520, smem+147968, flgS, xg1r, whh1p,
               hinB, cinB, y1wr, houtB, coutB, bid-16, nsteps);
  } else {
    const int gb = bid - 32;   // 0..223
    if (hasG0){
      for (int tile = gb; tile < ntG; tile += 224){
        gemm_body<4,true >(smem, xG0, wih0p, bias0, xg0w, VV, tile&3, tile>>2);
        __syncthreads();
      }
    }
    if (hasG1){
      for (int tile = gb; tile < ntG; tile += 224){
        gemm_body<8,false>(smem, y0rd, wih1p, bias1, xg1w, HH, tile&3, tile>>2);
        __syncthreads();
      }
    }
    if (hasFC){
      for (int tile = gb; tile < nsteps*4; tile += 224){
        fc_body(smem, y1fc, wfcp, bfc, outfc, tile);
        __syncthreads();
      }
    }
  }
}

// ---------------------------------------------------------------------------
extern "C" void kernel_launch(void* const* d_in, const int* in_sizes, int n_in,
                              void* d_out, int out_size, void* d_ws, size_t ws_size,
                              hipStream_t stream) {
  (void)in_sizes; (void)n_in; (void)out_size;
  const float* x    = (const float*)d_in[0];
  const float* h0   = (const float*)d_in[1];
  const float* c0   = (const float*)d_in[2];
  const float* Wih0 = (const float*)d_in[3];
  const float* Whh0 = (const float*)d_in[4];
  const float* bih0 = (const float*)d_in[5];
  const float* bhh0 = (const float*)d_in[6];
  const float* Wih1 = (const float*)d_in[7];
  const float* Whh1 = (const float*)d_in[8];
  const float* bih1 = (const float*)d_in[9];
  const float* bhh1 = (const float*)d_in[10];
  const float* Wfc  = (const float*)d_in[11];
  const float* bfc  = (const float*)d_in[12];
  float* out = (float*)d_out;

  // runtime chunk: TC=32 (~81MB ws) if available, else TC=16 (~44MB, proven)
  const int TCr  = (ws_size >= (size_t)82*1024*1024) ? 32 : 16;
  const int NCHr = TT / TCr;
  const size_t XGB = (size_t)TCr*BB*1024*2 + 524288;  // bytes/xg buf (+slack)
  const size_t Y0B = (size_t)TCr*BB*HH*2;

  char* p = (char*)d_ws;
  u16* xg0b[2]; u16* xg1b[2]; u16* y0b[2];
  xg0b[0] = (u16*)p; p += XGB;
  xg0b[1] = (u16*)p; p += XGB;
  xg1b[0] = (u16*)p; p += XGB;
  xg1b[1] = (u16*)p; p += XGB;
  y0b[0]  = (u16*)p; p += Y0B;
  y0b[1]  = (u16*)p; p += Y0B;
  u16* whh0p = (u16*)p; p += 524288;
  u16* whh1p = (u16*)p; p += 524288;
  u16* wih0p = (u16*)p; p += 262144;
  u16* wih1p = (u16*)p; p += 524288;
  u16* wfcp  = (u16*)p; p += 65536;
  float* bias0 = (float*)p; p += 4096;
  float* bias1 = (float*)p; p += 4096;
  float* hst0 = (float*)p; p += 262144;
  float* cst0 = (float*)p; p += 262144;
  float* hst1 = (float*)p; p += 262144;
  float* cst1 = (float*)p; p += 262144;

  u16* y1    = (u16*)d_out;          // bf16 y1 aliases out rows; FC rewrites
  float* hid = out + 16777216;       // them in-place 3 dispatches later
  float* cel = hid + 131072;

  pack_b<<<64 ,256,0,stream>>>(Wih0, wih0p, 1024,128);
  pack_b<<<128,256,0,stream>>>(Whh0, whh0p, 1024,256);
  pack_b<<<128,256,0,stream>>>(Wih1, wih1p, 1024,256);
  pack_b<<<128,256,0,stream>>>(Whh1, whh1p, 1024,256);
  pack_b<<<16 ,256,0,stream>>>(Wfc,  wfcp,  128,256);
  bias_sum<<<8,256,0,stream>>>(bih0,bhh0,bias0, bih1,bhh1,bias1);

  // prologue: G0(0)
  gemm_perm0<<<dim3(4, TCr*4),512,0,stream>>>(x, wih0p, bias0, xg0b[0]);

  for (int d = 0; d <= NCHr + 2; ++d){
    const int hasR0 = (d < NCHr);
    const int hasR1 = (d >= 2) && (d < NCHr + 2);
    const int hasG0 = (d + 1 < NCHr);
    const int hasG1 = (d >= 1) && (d - 1 < NCHr);
    const int hasFC = (d >= 3) && (d - 3 < NCHr);
    const int cR1 = hasR1 ? d-2 : 0;
    const int cG0 = hasG0 ? d+1 : 0;
    const int cFC = hasFC ? d-3 : 0;
    mega<<<256,512,0,stream>>>(
      hasR0, hasR1, hasG0, hasG1, hasFC, TCr,
      // R0(d)
      xg0b[d&1],
      (d==0) ? h0 : hst0, (d==0) ? c0 : cst0,
      y0b[d&1],
      (d==NCHr-1) ? hid : hst0, (d==NCHr-1) ? cel : cst0,
      // R1(d-2)
      xg1b[d&1],
      (cR1==0) ? (h0+65536) : hst1, (cR1==0) ? (c0+65536) : cst1,
      y1 + (size_t)cR1*TCr*BB*HH,
      (cR1==NCHr-1) ? (hid+65536) : hst1, (cR1==NCHr-1) ? (cel+65536) : cst1,
      // G0(d+1)
      x + (size_t)cG0*TCr*BB*VV, xg0b[(d+1)&1],
      // G1(d-1): reads y0(d-1), writes xg1(d-1)
      y0b[(d-1)&1], xg1b[(d-1)&1],
      // FC(d-3)
      y1 + (size_t)cFC*TCr*BB*HH, out + (size_t)cFC*TCr*BB*VV,
      wih0p, bias0, wih1p, bias1, whh0p, whh1p, wfcp, bfc);
  }
}

// Round 13
// 1601.432 us; speedup vs baseline: 1.7790x; 1.7790x over previous
//
#include <hip/hip_runtime.h>
#include <hip/hip_bf16.h>

#define DI __device__ __forceinline__

typedef short bf16x8 __attribute__((ext_vector_type(8)));
typedef float f32x4 __attribute__((ext_vector_type(4)));
typedef int   i32x4 __attribute__((ext_vector_type(4)));
typedef unsigned short u16;

constexpr int TT = 512, BB = 256, HH = 256, VV = 128;

DI u16 f2b(float f){ __hip_bfloat16 h = __float2bfloat16(f); u16 r; __builtin_memcpy(&r,&h,2); return r; }
DI float b2f(u16 v){ unsigned u = ((unsigned)v)<<16; float f; __builtin_memcpy(&f,&u,4); return f; }
DI f32x4 mfma16(bf16x8 a, bf16x8 b, f32x4 c){ return __builtin_amdgcn_mfma_f32_16x16x32_bf16(a,b,c,0,0,0); }

// ---------------------------------------------------------------------------
// pack W [N][K] f32 -> B-fragment layout: frag(ntg,kt,lane)[j] =
//   bf16( W[ntg*16 + (lane&15)][kt*32 + (lane>>4)*8 + j] ), linear at tid*8.
// ---------------------------------------------------------------------------
__global__ void pack_b(const float* __restrict__ W, u16* __restrict__ o, int N, int K){
  const int tid = blockIdx.x*256 + threadIdx.x;
  const int KT = K >> 5;
  const int total = (N>>4)*KT*64;
  if (tid >= total) return;
  const int lane = tid & 63;
  const int rest = tid >> 6;
  const int kt  = rest % KT;
  const int ntg = rest / KT;
  const int n  = (ntg<<4) + (lane&15);
  const int k0 = (kt<<5) + ((lane>>4)<<3);
  const float* s = W + (size_t)n*K + k0;
  bf16x8 pv;
#pragma unroll
  for (int j=0;j<8;++j) pv[j] = (short)f2b(s[j]);
  *(bf16x8*)(o + (size_t)tid*8) = pv;
}

__global__ void bias_sum(const float* a0,const float* b0,float* o0,
                         const float* a1,const float* b1,float* o1){
  int i = blockIdx.x*256 + threadIdx.x;
  if (i < 1024) o0[i] = a0[i] + b0[i];
  else if (i < 2048) { int j=i-1024; o1[j] = a1[j] + b1[j]; }
}

// ---------------------------------------------------------------------------
// GEMM body -> quadrant-split permuted bf16 xg, coalesced epilogue.
// xg u16 index: ((((t*4 + q4)*16 + bg)*8 + wr)*64 + l)*8 + p*4 + i
//   gate col = q4*256 + wr*32 + p*16 + l15, batch row = t*256+bg*16+4*g4+i.
// Block (bx=q4, by): rows [by*64,+64) (single t), cols [bx*256,+256).
// ---------------------------------------------------------------------------
template<int KT, bool AF32>
DI void gemm_body(char* smem, const void* __restrict__ A_,
                  const u16* __restrict__ Bp, const float* __restrict__ bias,
                  u16* __restrict__ xgp, int lda, int bx, int by)
{
  constexpr int NT = 8;
  const int tid = threadIdx.x;
  const int l = tid & 63, w = tid >> 6;
  const int l15 = l & 15, g4 = l >> 4;
  const int mw = w >> 1, nw = w & 1;
  const int col0 = bx * 256;
  const int row0 = by * 64;

  { // stage packed-B slice (contiguous) into LDS
    const int n16 = 2*NT*KT*64;
    const i32x4* src = (const i32x4*)(Bp + (size_t)(col0>>4)*KT*64*8);
    i32x4* dst = (i32x4*)smem;
    for (int i=tid; i<n16; i+=512) dst[i] = src[i];
  }
  __syncthreads();

  f32x4 acc[NT];
#pragma unroll
  for (int nt=0; nt<NT; ++nt) acc[nt] = (f32x4){0.f,0.f,0.f,0.f};

  const int rowA = row0 + mw*16 + l15;
#pragma unroll
  for (int kt=0; kt<KT; ++kt){
    bf16x8 a;
    const int k0 = kt*32 + g4*8;
    if constexpr (AF32){
      const float* ap = (const float*)A_ + (size_t)rowA*lda + k0;
      const f32x4 x0 = *(const f32x4*)ap;
      const f32x4 x1 = *(const f32x4*)(ap+4);
#pragma unroll
      for (int j=0;j<4;++j){ a[j] = (short)f2b(x0[j]); a[j+4] = (short)f2b(x1[j]); }
    } else {
      a = *(const bf16x8*)((const u16*)A_ + (size_t)rowA*lda + k0);
    }
#pragma unroll
    for (int nt=0; nt<NT; ++nt){
      const bf16x8 b = *(const bf16x8*)(smem + (size_t)(((nw*NT+nt)*KT + kt)*64 + l)*16);
      acc[nt] = mfma16(a,b,acc[nt]);
    }
  }

  // coalesced permuted epilogue: one 16B store per wr
  const int t  = row0 >> 8;
  const int bg = ((row0 & 255) >> 4) + mw;
#pragma unroll
  for (int j=0;j<4;++j){
    bf16x8 pk;
#pragma unroll
    for (int p=0;p<2;++p){
      const int nt = 2*j + p;
      const float bv = bias[col0 + (nw*8+nt)*16 + l15];
#pragma unroll
      for (int i=0;i<4;++i) pk[p*4+i] = (short)f2b(acc[nt][i] + bv);
    }
    const int wr = nw*4 + j;
    *(bf16x8*)(xgp + ((((size_t)(t*4 + bx)*16 + bg)*8 + wr)*64 + l)*8) = pk;
  }
}

__global__ __launch_bounds__(512,2) void gemm_perm0(const float* A, const u16* Bp,
    const float* bias, u16* xgp){
  __shared__ char smem[65536];
  gemm_body<4,true>(smem, A, Bp, bias, xgp, VV, blockIdx.x, blockIdx.y);
}

// ---------------------------------------------------------------------------
// FC body: C[64 x 128] f32 = A[64 x 256] bf16 @ WfcP + bfc, in-place over A
// rows (pre-epilogue barrier). KT=8, NT=4 (one col block). LDS 65536.
// ---------------------------------------------------------------------------
DI void fc_body(char* smem, const u16* __restrict__ A_,
                const u16* __restrict__ Bp, const float* __restrict__ bias,
                float* __restrict__ C_, int by)
{
  constexpr int KT = 8, NT = 4;
  const int tid = threadIdx.x;
  const int l = tid & 63, w = tid >> 6;
  const int l15 = l & 15, g4 = l >> 4;
  const int mw = w >> 1, nw = w & 1;
  const int row0 = by * 64;

  {
    const int n16 = 2*NT*KT*64;
    const i32x4* src = (const i32x4*)Bp;
    i32x4* dst = (i32x4*)smem;
    for (int i=tid; i<n16; i+=512) dst[i] = src[i];
  }
  __syncthreads();

  f32x4 acc[NT];
#pragma unroll
  for (int nt=0; nt<NT; ++nt) acc[nt] = (f32x4){0.f,0.f,0.f,0.f};

  const int rowA = row0 + mw*16 + l15;
#pragma unroll
  for (int kt=0; kt<KT; ++kt){
    const bf16x8 a = *(const bf16x8*)(A_ + (size_t)rowA*HH + kt*32 + g4*8);
#pragma unroll
    for (int nt=0; nt<NT; ++nt){
      const bf16x8 b = *(const bf16x8*)(smem + (size_t)(((nw*NT+nt)*KT + kt)*64 + l)*16);
      acc[nt] = mfma16(a,b,acc[nt]);
    }
  }

  __syncthreads();   // drain all A-loads in block before in-place C-stores

#pragma unroll
  for (int nt=0; nt<NT; ++nt){
    const int col = (nw*NT+nt)*16 + l15;
    const float bv = bias[col];
#pragma unroll
    for (int i=0;i<4;++i)
      C_[(size_t)(row0 + mw*16 + 4*g4 + i)*VV + col] = acc[nt][i] + bv;
  }
}

// ---------------------------------------------------------------------------
// Recurrent chunk body (nsteps even) — CONSOLIDATED best configuration.
// Wave w owns hidden units [32w,32w+32). W: i,f resident regs (128);
// o tiles in LDS; g tiles streamed from L2 (R9-bench layout, 88.5 us).
// h double-buffered in LDS; xg 4x16B loads/lane/step prefetched 1 ahead.
// Nonlin: fused reciprocals (exact algebra; validated absmax-identical).
// y-stores: h(t) kept in regs (hb[8]); LDS write -> barrier -> THEN y-stores,
// so their vmcnt drain lands at the NEXT step's barrier (fully hidden) with
// zero extra LDS traffic and no scheduling pragmas.
// ---------------------------------------------------------------------------
DI void rec_body(char* smW, char* smH0, char* smH1,
    const u16* __restrict__ xg, const u16* __restrict__ Whhp,
    const float* h_in, const float* c_in, u16* __restrict__ y,
    float* hout, float* cout, int bg, int nsteps)
{
  const int tid = threadIdx.x;
  const int w = tid >> 6, l = tid & 63;
  const int l15 = l & 15, g4 = l >> 4;
  const int b0 = bg * 16;

  const u16* xt = xg + ((size_t)(bg*8 + w)*64 + l)*8;   // +262144 u16/step
  u16* yp = y + (size_t)(b0 + 4*g4)*256 + 32*w + l15;   // +65536 u16/step

  bf16x8 xsv[4];
#pragma unroll
  for (int q=0;q<4;++q) xsv[q] = *(const bf16x8*)(xt + q*65536);

  // resident W: gate i (nt 0,1) and f (nt 2,3)
  bf16x8 Wr[4][8];
#pragma unroll
  for (int nt=0; nt<4; ++nt){
    const int ntg = ((nt>>1)<<4) + (w<<1) + (nt&1);
#pragma unroll
    for (int kt=0; kt<8; ++kt)
      Wr[nt][kt] = *(const bf16x8*)(Whhp + (((size_t)ntg*8 + kt)*64 + l)*8);
  }
  // o-gate tiles -> LDS in frag layout
#pragma unroll
  for (int ntl=0; ntl<2; ++ntl){
    const int ntg = 48 + (w<<1) + ntl;
#pragma unroll
    for (int kt=0; kt<8; ++kt){
      bf16x8 v = *(const bf16x8*)(Whhp + (((size_t)ntg*8 + kt)*64 + l)*8);
      *(bf16x8*)(smW + (size_t)((w*16 + ntl*8 + kt)*64 + l)*16) = v;
    }
  }
  // streamed g tiles: per-lane base pointers; frag kt at +kt*512 (u16)
  const u16* wg0 = Whhp + (((size_t)(32 + 2*w)*8)*64 + l)*8;
  const u16* wg1 = Whhp + (((size_t)(33 + 2*w)*8)*64 + l)*8;
  bf16x8 p00 = *(const bf16x8*)(wg0);
  bf16x8 p01 = *(const bf16x8*)(wg0 + 512);
  bf16x8 p10 = *(const bf16x8*)(wg1);
  bf16x8 p11 = *(const bf16x8*)(wg1 + 512);

  float c[2][4];
#pragma unroll
  for (int hf=0; hf<2; ++hf)
#pragma unroll
    for (int i=0;i<4;++i){
      const int b  = 4*g4 + i;
      const int jh = 32*w + 16*hf + l15;
      c[hf][i] = c_in[(size_t)(b0+b)*256 + jh];
      *(u16*)(smH0 + (size_t)b*528 + 2*jh) = f2b(h_in[(size_t)(b0+b)*256 + jh]);
    }
  __syncthreads();

  for (int t = 0; t < nsteps; ++t) {
    const char* hrd = (t&1) ? smH1 : smH0;
    char*       hwr = (t&1) ? smH0 : smH1;

    bf16x8 gA[8], gB[8];
    gA[0]=p00; gA[1]=p01; gB[0]=p10; gB[1]=p11;

    // kt=0: C-input = staged xg(t)
    gA[2] = *(const bf16x8*)(wg0 + 1024);
    gB[2] = *(const bf16x8*)(wg1 + 1024);
    const bf16x8 a0 = *(const bf16x8*)(hrd + (size_t)l15*528 + g4*16);
    f32x4 acc[8];
#pragma unroll
    for (int nt=0; nt<4; ++nt){
      f32x4 x0;
#pragma unroll
      for (int i=0;i<4;++i) x0[i] = b2f((u16)xsv[nt>>1][(nt&1)*4+i]);
      acc[nt] = mfma16(a0, Wr[nt][0], x0);
    }
    {
      f32x4 x4, x5;
#pragma unroll
      for (int i=0;i<4;++i){ x4[i] = b2f((u16)xsv[2][i]); x5[i] = b2f((u16)xsv[2][4+i]); }
      acc[4] = mfma16(a0, gA[0], x4);
      acc[5] = mfma16(a0, gB[0], x5);
    }
#pragma unroll
    for (int ntl=0; ntl<2; ++ntl){
      const int nt = 6+ntl;
      f32x4 x0;
#pragma unroll
      for (int i=0;i<4;++i) x0[i] = b2f((u16)xsv[3][ntl*4+i]);
      const bf16x8 wl = *(const bf16x8*)(smW + (size_t)((w*16 + ntl*8)*64 + l)*16);
      acc[nt] = mfma16(a0, wl, x0);
    }
    xt += 262144;                       // prefetch next step's xg (slack-padded)
#pragma unroll
    for (int q=0;q<4;++q) xsv[q] = *(const bf16x8*)(xt + q*65536);

#pragma unroll
    for (int kt=1; kt<8; ++kt){
      if (kt < 6){                      // stream g frag kt+2, 2-ahead
        gA[kt+2] = *(const bf16x8*)(wg0 + (size_t)(kt+2)*512);
        gB[kt+2] = *(const bf16x8*)(wg1 + (size_t)(kt+2)*512);
      }
      const bf16x8 a = *(const bf16x8*)(hrd + (size_t)l15*528 + kt*64 + g4*16);
#pragma unroll
      for (int nt=0; nt<4; ++nt) acc[nt] = mfma16(a, Wr[nt][kt], acc[nt]);
      acc[4] = mfma16(a, gA[kt], acc[4]);
      acc[5] = mfma16(a, gB[kt], acc[5]);
#pragma unroll
      for (int ntl=0; ntl<2; ++ntl){
        const bf16x8 wl = *(const bf16x8*)(smW + (size_t)((w*16 + ntl*8 + kt)*64 + l)*16);
        acc[6+ntl] = mfma16(a, wl, acc[6+ntl]);
      }
    }

    // refresh persistent stream frags for next step (latency hidden by nonlin)
    p00 = *(const bf16x8*)(wg0);
    p01 = *(const bf16x8*)(wg0 + 512);
    p10 = *(const bf16x8*)(wg1);
    p11 = *(const bf16x8*)(wg1 + 512);

    // nonlinearity + state update: fused-reciprocal form (exact algebra)
    u16 hb[8];
#pragma unroll
    for (int hf=0; hf<2; ++hf){
#pragma unroll
      for (int i=0;i<4;++i){
        const float xi = acc[0+hf][i];
        const float xf = acc[2+hf][i];
        const float xG = acc[4+hf][i];
        const float xo = acc[6+hf][i];
        const float ai = __builtin_amdgcn_exp2f(-1.4426950408889634f*xi);
        const float af = __builtin_amdgcn_exp2f(-1.4426950408889634f*xf);
        const float eg = __builtin_amdgcn_exp2f(-2.8853900817779268f*xG);
        const float rig = __builtin_amdgcn_rcpf((1.0f+ai)*(1.0f+eg));
        const float rf  = __builtin_amdgcn_rcpf(1.0f+af);
        const float cc  = c[hf][i]*rf + (1.0f-eg)*rig;   // sig(f)*c + sig(i)*tanh(g)
        c[hf][i] = cc;
        const float ao = __builtin_amdgcn_exp2f(-1.4426950408889634f*xo);
        const float dc = __builtin_amdgcn_exp2f(-2.8853900817779268f*cc);
        const float roc = __builtin_amdgcn_rcpf((1.0f+ao)*(1.0f+dc));
        const float hh  = (1.0f-dc)*roc;                 // sig(o)*tanh(c)
        hb[hf*4+i] = f2b(hh);
        *(u16*)(hwr + (size_t)(4*g4+i)*528 + 2*(32*w + 16*hf + l15)) = hb[hf*4+i];
      }
    }
    __syncthreads();   // drains LDS h-writes (+ y-stores of step t-1)

    // y-stores AFTER the barrier, from registers: their vmcnt(0) drain is
    // deferred to the NEXT step's barrier -> fully hidden under step t+1.
#pragma unroll
    for (int hf=0; hf<2; ++hf)
#pragma unroll
      for (int i=0;i<4;++i)
        yp[(size_t)i*256 + hf*16] = hb[hf*4+i];
    yp += 65536;
  }

  // final state write-back (nsteps even -> last h in smH0)
#pragma unroll
  for (int hf=0; hf<2; ++hf)
#pragma unroll
    for (int i=0;i<4;++i){
      const int b  = 4*g4 + i;
      const int jh = 32*w + 16*hf + l15;
      hout[(size_t)(b0+b)*256 + jh] = b2f(*(u16*)(smH0 + (size_t)b*528 + 2*jh));
      cout[(size_t)(b0+b)*256 + jh] = c[hf][i];
    }
}

// ---------------------------------------------------------------------------
// Mega dispatch d — ALL work is cross-dispatch independent (kernel-boundary
// coherence only; zero atomics/fences, per Guideline 16):
//   blocks 0-15 : R0(d)    layer-0 rec chunk d
//   blocks 16-31: R1(d-2)  layer-1 rec chunk d-2
//   blocks 32+  : chasers: G0(d+1), G1(d-1), FC(d-3)
// Grid 256 x 512thr, LDS 148K -> 1 block/CU.
// ---------------------------------------------------------------------------
__global__ __launch_bounds__(512,2) void mega(
    int hasR0, int hasR1, int hasG0, int hasG1, int hasFC, int nsteps,
    const u16* __restrict__ xg0r, const float* hinA, const float* cinA,
    u16* y0wr, float* houtA, float* coutA,
    const u16* __restrict__ xg1r, const float* hinB, const float* cinB,
    u16* y1wr, float* houtB, float* coutB,
    const float* __restrict__ xG0, u16* __restrict__ xg0w,
    const u16* __restrict__ y0rd, u16* __restrict__ xg1w,
    const u16* __restrict__ y1fc, float* __restrict__ outfc,
    const u16* __restrict__ wih0p, const float* __restrict__ bias0,
    const u16* __restrict__ wih1p, const float* __restrict__ bias1,
    const u16* __restrict__ whh0p, const u16* __restrict__ whh1p,
    const u16* __restrict__ wfcp,  const float* __restrict__ bfc)
{
  __shared__ char smem[147968];
  const int bid = (int)blockIdx.x;
  const int ntG = nsteps * 16;

  if (bid < 16){
    if (hasR0)
      rec_body(smem, smem+131072, smem+131072+8448, xg0r, whh0p,
               hinA, cinA, y0wr, houtA, coutA, bid, nsteps);
  } else if (bid < 32){
    if (hasR1)
      rec_body(smem, smem+131072, smem+131072+8448, xg1r, whh1p,
               hinB, cinB, y1wr, houtB, coutB, bid-16, nsteps);
  } else {
    const int gb = bid - 32;   // 0..223
    if (hasG0){
      for (int tile = gb; tile < ntG; tile += 224){
        gemm_body<4,true >(smem, xG0, wih0p, bias0, xg0w, VV, tile&3, tile>>2);
        __syncthreads();
      }
    }
    if (hasG1){
      for (int tile = gb; tile < ntG; tile += 224){
        gemm_body<8,false>(smem, y0rd, wih1p, bias1, xg1w, HH, tile&3, tile>>2);
        __syncthreads();
      }
    }
    if (hasFC){
      for (int tile = gb; tile < nsteps*4; tile += 224){
        fc_body(smem, y1fc, wfcp, bfc, outfc, tile);
        __syncthreads();
      }
    }
  }
}

// ---------------------------------------------------------------------------
extern "C" void kernel_launch(void* const* d_in, const int* in_sizes, int n_in,
                              void* d_out, int out_size, void* d_ws, size_t ws_size,
                              hipStream_t stream) {
  (void)in_sizes; (void)n_in; (void)out_size;
  const float* x    = (const float*)d_in[0];
  const float* h0   = (const float*)d_in[1];
  const float* c0   = (const float*)d_in[2];
  const float* Wih0 = (const float*)d_in[3];
  const float* Whh0 = (const float*)d_in[4];
  const float* bih0 = (const float*)d_in[5];
  const float* bhh0 = (const float*)d_in[6];
  const float* Wih1 = (const float*)d_in[7];
  const float* Whh1 = (const float*)d_in[8];
  const float* bih1 = (const float*)d_in[9];
  const float* bhh1 = (const float*)d_in[10];
  const float* Wfc  = (const float*)d_in[11];
  const float* bfc  = (const float*)d_in[12];
  float* out = (float*)d_out;

  // runtime chunk: TC=32 (~81MB ws) if available, else TC=16 (~44MB, proven)
  const int TCr  = (ws_size >= (size_t)82*1024*1024) ? 32 : 16;
  const int NCHr = TT / TCr;
  const size_t XGB = (size_t)TCr*BB*1024*2 + 524288;  // bytes/xg buf (+slack)
  const size_t Y0B = (size_t)TCr*BB*HH*2;

  char* p = (char*)d_ws;
  u16* xg0b[2]; u16* xg1b[2]; u16* y0b[2];
  xg0b[0] = (u16*)p; p += XGB;
  xg0b[1] = (u16*)p; p += XGB;
  xg1b[0] = (u16*)p; p += XGB;
  xg1b[1] = (u16*)p; p += XGB;
  y0b[0]  = (u16*)p; p += Y0B;
  y0b[1]  = (u16*)p; p += Y0B;
  u16* whh0p = (u16*)p; p += 524288;
  u16* whh1p = (u16*)p; p += 524288;
  u16* wih0p = (u16*)p; p += 262144;
  u16* wih1p = (u16*)p; p += 524288;
  u16* wfcp  = (u16*)p; p += 65536;
  float* bias0 = (float*)p; p += 4096;
  float* bias1 = (float*)p; p += 4096;
  float* hst0 = (float*)p; p += 262144;
  float* cst0 = (float*)p; p += 262144;
  float* hst1 = (float*)p; p += 262144;
  float* cst1 = (float*)p; p += 262144;

  u16* y1    = (u16*)d_out;          // bf16 y1 aliases out rows; FC rewrites
  float* hid = out + 16777216;       // them in-place 3 dispatches later
  float* cel = hid + 131072;

  pack_b<<<64 ,256,0,stream>>>(Wih0, wih0p, 1024,128);
  pack_b<<<128,256,0,stream>>>(Whh0, whh0p, 1024,256);
  pack_b<<<128,256,0,stream>>>(Wih1, wih1p, 1024,256);
  pack_b<<<128,256,0,stream>>>(Whh1, whh1p, 1024,256);
  pack_b<<<16 ,256,0,stream>>>(Wfc,  wfcp,  128,256);
  bias_sum<<<8,256,0,stream>>>(bih0,bhh0,bias0, bih1,bhh1,bias1);

  // prologue: G0(0)
  gemm_perm0<<<dim3(4, TCr*4),512,0,stream>>>(x, wih0p, bias0, xg0b[0]);

  for (int d = 0; d <= NCHr + 2; ++d){
    const int hasR0 = (d < NCHr);
    const int hasR1 = (d >= 2) && (d < NCHr + 2);
    const int hasG0 = (d + 1 < NCHr);
    const int hasG1 = (d >= 1) && (d - 1 < NCHr);
    const int hasFC = (d >= 3) && (d - 3 < NCHr);
    const int cR1 = hasR1 ? d-2 : 0;
    const int cG0 = hasG0 ? d+1 : 0;
    const int cFC = hasFC ? d-3 : 0;
    mega<<<256,512,0,stream>>>(
      hasR0, hasR1, hasG0, hasG1, hasFC, TCr,
      // R0(d)
      xg0b[d&1],
      (d==0) ? h0 : hst0, (d==0) ? c0 : cst0,
      y0b[d&1],
      (d==NCHr-1) ? hid : hst0, (d==NCHr-1) ? cel : cst0,
      // R1(d-2)
      xg1b[d&1],
      (cR1==0) ? (h0+65536) : hst1, (cR1==0) ? (c0+65536) : cst1,
      y1 + (size_t)cR1*TCr*BB*HH,
      (cR1==NCHr-1) ? (hid+65536) : hst1, (cR1==NCHr-1) ? (cel+65536) : cst1,
      // G0(d+1)
      x + (size_t)cG0*TCr*BB*VV, xg0b[(d+1)&1],
      // G1(d-1): reads y0(d-1), writes xg1(d-1)
      y0b[(d-1)&1], xg1b[(d-1)&1],
      // FC(d-3)
      y1 + (size_t)cFC*TCr*BB*HH, out + (size_t)cFC*TCr*BB*VV,
      wih0p, bias0, wih1p, bias1, whh0p, whh1p, wfcp, bfc);
  }
}

// Round 14
// 1525.454 us; speedup vs baseline: 1.8676x; 1.0498x over previous
//
#include <hip/hip_runtime.h>
#include <hip/hip_bf16.h>

#define DI __device__ __forceinline__

typedef short bf16x8 __attribute__((ext_vector_type(8)));
typedef float f32x4 __attribute__((ext_vector_type(4)));
typedef int   i32x4 __attribute__((ext_vector_type(4)));
typedef unsigned short u16;

constexpr int TT = 512, BB = 256, HH = 256, VV = 128;

DI u16 f2b(float f){ __hip_bfloat16 h = __float2bfloat16(f); u16 r; __builtin_memcpy(&r,&h,2); return r; }
DI float b2f(u16 v){ unsigned u = ((unsigned)v)<<16; float f; __builtin_memcpy(&f,&u,4); return f; }
DI float fsig(float x){ return __builtin_amdgcn_rcpf(1.0f + __builtin_amdgcn_exp2f(-1.4426950408889634f*x)); }
DI float ftanh(float x){ return 1.0f - 2.0f*__builtin_amdgcn_rcpf(1.0f + __builtin_amdgcn_exp2f(2.8853900817779268f*x)); }
DI f32x4 mfma16(bf16x8 a, bf16x8 b, f32x4 c){ return __builtin_amdgcn_mfma_f32_16x16x32_bf16(a,b,c,0,0,0); }

// ---------------------------------------------------------------------------
// pack W [N][K] f32 -> B-fragment layout: frag(ntg,kt,lane)[j] =
//   bf16( W[ntg*16 + (lane&15)][kt*32 + (lane>>4)*8 + j] ), linear at tid*8.
// ---------------------------------------------------------------------------
__global__ void pack_b(const float* __restrict__ W, u16* __restrict__ o, int N, int K){
  const int tid = blockIdx.x*256 + threadIdx.x;
  const int KT = K >> 5;
  const int total = (N>>4)*KT*64;
  if (tid >= total) return;
  const int lane = tid & 63;
  const int rest = tid >> 6;
  const int kt  = rest % KT;
  const int ntg = rest / KT;
  const int n  = (ntg<<4) + (lane&15);
  const int k0 = (kt<<5) + ((lane>>4)<<3);
  const float* s = W + (size_t)n*K + k0;
  bf16x8 pv;
#pragma unroll
  for (int j=0;j<8;++j) pv[j] = (short)f2b(s[j]);
  *(bf16x8*)(o + (size_t)tid*8) = pv;
}

__global__ void bias_sum(const float* a0,const float* b0,float* o0,
                         const float* a1,const float* b1,float* o1){
  int i = blockIdx.x*256 + threadIdx.x;
  if (i < 1024) o0[i] = a0[i] + b0[i];
  else if (i < 2048) { int j=i-1024; o1[j] = a1[j] + b1[j]; }
}

// ---------------------------------------------------------------------------
// GEMM body -> quadrant-split permuted bf16 xg, coalesced epilogue.
// xg u16 index: ((((t*4 + q4)*16 + bg)*8 + wr)*64 + l)*8 + p*4 + i
//   gate col = q4*256 + wr*32 + p*16 + l15, batch row = t*256+bg*16+4*g4+i.
// Block (bx=q4, by): rows [by*64,+64) (single t), cols [bx*256,+256).
// ---------------------------------------------------------------------------
template<int KT, bool AF32>
DI void gemm_body(char* smem, const void* __restrict__ A_,
                  const u16* __restrict__ Bp, const float* __restrict__ bias,
                  u16* __restrict__ xgp, int lda, int bx, int by)
{
  constexpr int NT = 8;
  const int tid = threadIdx.x;
  const int l = tid & 63, w = tid >> 6;
  const int l15 = l & 15, g4 = l >> 4;
  const int mw = w >> 1, nw = w & 1;
  const int col0 = bx * 256;
  const int row0 = by * 64;

  { // stage packed-B slice (contiguous) into LDS
    const int n16 = 2*NT*KT*64;
    const i32x4* src = (const i32x4*)(Bp + (size_t)(col0>>4)*KT*64*8);
    i32x4* dst = (i32x4*)smem;
    for (int i=tid; i<n16; i+=512) dst[i] = src[i];
  }
  __syncthreads();

  f32x4 acc[NT];
#pragma unroll
  for (int nt=0; nt<NT; ++nt) acc[nt] = (f32x4){0.f,0.f,0.f,0.f};

  const int rowA = row0 + mw*16 + l15;
#pragma unroll
  for (int kt=0; kt<KT; ++kt){
    bf16x8 a;
    const int k0 = kt*32 + g4*8;
    if constexpr (AF32){
      const float* ap = (const float*)A_ + (size_t)rowA*lda + k0;
      const f32x4 x0 = *(const f32x4*)ap;
      const f32x4 x1 = *(const f32x4*)(ap+4);
#pragma unroll
      for (int j=0;j<4;++j){ a[j] = (short)f2b(x0[j]); a[j+4] = (short)f2b(x1[j]); }
    } else {
      a = *(const bf16x8*)((const u16*)A_ + (size_t)rowA*lda + k0);
    }
#pragma unroll
    for (int nt=0; nt<NT; ++nt){
      const bf16x8 b = *(const bf16x8*)(smem + (size_t)(((nw*NT+nt)*KT + kt)*64 + l)*16);
      acc[nt] = mfma16(a,b,acc[nt]);
    }
  }

  // coalesced permuted epilogue: one 16B store per wr
  const int t  = row0 >> 8;
  const int bg = ((row0 & 255) >> 4) + mw;
#pragma unroll
  for (int j=0;j<4;++j){
    bf16x8 pk;
#pragma unroll
    for (int p=0;p<2;++p){
      const int nt = 2*j + p;
      const float bv = bias[col0 + (nw*8+nt)*16 + l15];
#pragma unroll
      for (int i=0;i<4;++i) pk[p*4+i] = (short)f2b(acc[nt][i] + bv);
    }
    const int wr = nw*4 + j;
    *(bf16x8*)(xgp + ((((size_t)(t*4 + bx)*16 + bg)*8 + wr)*64 + l)*8) = pk;
  }
}

__global__ __launch_bounds__(512,2) void gemm_perm0(const float* A, const u16* Bp,
    const float* bias, u16* xgp){
  __shared__ char smem[65536];
  gemm_body<4,true>(smem, A, Bp, bias, xgp, VV, blockIdx.x, blockIdx.y);
}

// ---------------------------------------------------------------------------
// FC body: C[64 x 128] f32 = A[64 x 256] bf16 @ WfcP + bfc, in-place over A
// rows (pre-epilogue barrier). KT=8, NT=4 (one col block). LDS 65536.
// ---------------------------------------------------------------------------
DI void fc_body(char* smem, const u16* __restrict__ A_,
                const u16* __restrict__ Bp, const float* __restrict__ bias,
                float* __restrict__ C_, int by)
{
  constexpr int KT = 8, NT = 4;
  const int tid = threadIdx.x;
  const int l = tid & 63, w = tid >> 6;
  const int l15 = l & 15, g4 = l >> 4;
  const int mw = w >> 1, nw = w & 1;
  const int row0 = by * 64;

  {
    const int n16 = 2*NT*KT*64;
    const i32x4* src = (const i32x4*)Bp;
    i32x4* dst = (i32x4*)smem;
    for (int i=tid; i<n16; i+=512) dst[i] = src[i];
  }
  __syncthreads();

  f32x4 acc[NT];
#pragma unroll
  for (int nt=0; nt<NT; ++nt) acc[nt] = (f32x4){0.f,0.f,0.f,0.f};

  const int rowA = row0 + mw*16 + l15;
#pragma unroll
  for (int kt=0; kt<KT; ++kt){
    const bf16x8 a = *(const bf16x8*)(A_ + (size_t)rowA*HH + kt*32 + g4*8);
#pragma unroll
    for (int nt=0; nt<NT; ++nt){
      const bf16x8 b = *(const bf16x8*)(smem + (size_t)(((nw*NT+nt)*KT + kt)*64 + l)*16);
      acc[nt] = mfma16(a,b,acc[nt]);
    }
  }

  __syncthreads();   // drain all A-loads in block before in-place C-stores

#pragma unroll
  for (int nt=0; nt<NT; ++nt){
    const int col = (nw*NT+nt)*16 + l15;
    const float bv = bias[col];
#pragma unroll
    for (int i=0;i<4;++i)
      C_[(size_t)(row0 + mw*16 + 4*g4 + i)*VV + col] = acc[nt][i] + bv;
  }
}

// ---------------------------------------------------------------------------
// Recurrent chunk body (nsteps even). Wave w owns hidden units [32w,32w+32);
// n-tiles 0..5 (i,f,g) in VGPRs, 6..7 (o) in LDS. h double-buffered in LDS.
// xg quadrant layout: 4 x 16B loads/lane/step, prefetched one step ahead.
// BEST-MEASURED configuration (R7 bench: mega 89.5us, total 1526.8us).
// Structural floor: ~2.77us/step — MFMA->VALU(nonlin)->LDS->barrier latency
// chain of the serial recurrence on 16 CUs/layer; seven interventions
// (xg path x2, W path x3, barrier scheme x2) all confirmed insensitivity.
// ---------------------------------------------------------------------------
DI void rec_body(char* smW, char* smH0, char* smH1,
    const u16* __restrict__ xg, const u16* __restrict__ Whhp,
    const float* h_in, const float* c_in, u16* __restrict__ y,
    float* hout, float* cout, int bg, int nsteps)
{
  const int tid = threadIdx.x;
  const int w = tid >> 6, l = tid & 63;
  const int l15 = l & 15, g4 = l >> 4;
  const int b0 = bg * 16;

  const u16* xt = xg + ((size_t)(bg*8 + w)*64 + l)*8;   // +262144 u16/step
  u16* yp = y + (size_t)(b0 + 4*g4)*256 + 32*w + l15;   // +65536 u16/step

  bf16x8 xsv[4];
#pragma unroll
  for (int q=0;q<4;++q) xsv[q] = *(const bf16x8*)(xt + q*65536);

  bf16x8 Wr[6][8];
#pragma unroll
  for (int nt=0; nt<6; ++nt){
    const int ntg = ((nt>>1)<<4) + (w<<1) + (nt&1);
#pragma unroll
    for (int kt=0; kt<8; ++kt)
      Wr[nt][kt] = *(const bf16x8*)(Whhp + (((size_t)ntg*8 + kt)*64 + l)*8);
  }
#pragma unroll
  for (int ntl=0; ntl<2; ++ntl){
    const int ntg = 48 + (w<<1) + ntl;
#pragma unroll
    for (int kt=0; kt<8; ++kt){
      bf16x8 v = *(const bf16x8*)(Whhp + (((size_t)ntg*8 + kt)*64 + l)*8);
      *(bf16x8*)(smW + (size_t)((w*16 + ntl*8 + kt)*64 + l)*16) = v;
    }
  }

  float c[2][4];
#pragma unroll
  for (int hf=0; hf<2; ++hf)
#pragma unroll
    for (int i=0;i<4;++i){
      const int b  = 4*g4 + i;
      const int jh = 32*w + 16*hf + l15;
      c[hf][i] = c_in[(size_t)(b0+b)*256 + jh];
      *(u16*)(smH0 + (size_t)b*528 + 2*jh) = f2b(h_in[(size_t)(b0+b)*256 + jh]);
    }
  __syncthreads();

  for (int t = 0; t < nsteps; ++t) {
    const char* hrd = (t&1) ? smH1 : smH0;
    char*       hwr = (t&1) ? smH0 : smH1;

    // kt=0: C-input = staged xg(t); then restage xg(t+1) (slack-padded buf)
    const bf16x8 a0 = *(const bf16x8*)(hrd + (size_t)l15*528 + g4*16);
    f32x4 acc[8];
#pragma unroll
    for (int nt=0; nt<6; ++nt){
      f32x4 x0;
#pragma unroll
      for (int i=0;i<4;++i) x0[i] = b2f((u16)xsv[nt>>1][(nt&1)*4+i]);
      acc[nt] = mfma16(a0, Wr[nt][0], x0);
    }
#pragma unroll
    for (int ntl=0; ntl<2; ++ntl){
      const int nt = 6+ntl;
      f32x4 x0;
#pragma unroll
      for (int i=0;i<4;++i) x0[i] = b2f((u16)xsv[nt>>1][(nt&1)*4+i]);
      const bf16x8 wl = *(const bf16x8*)(smW + (size_t)((w*16 + ntl*8)*64 + l)*16);
      acc[nt] = mfma16(a0, wl, x0);
    }
    xt += 262144;
#pragma unroll
    for (int q=0;q<4;++q) xsv[q] = *(const bf16x8*)(xt + q*65536);

#pragma unroll
    for (int kt=1; kt<8; ++kt){
      const bf16x8 a = *(const bf16x8*)(hrd + (size_t)l15*528 + kt*64 + g4*16);
#pragma unroll
      for (int nt=0; nt<6; ++nt) acc[nt] = mfma16(a, Wr[nt][kt], acc[nt]);
#pragma unroll
      for (int ntl=0; ntl<2; ++ntl){
        const bf16x8 wl = *(const bf16x8*)(smW + (size_t)((w*16 + ntl*8 + kt)*64 + l)*16);
        acc[6+ntl] = mfma16(a, wl, acc[6+ntl]);
      }
    }

#pragma unroll
    for (int hf=0; hf<2; ++hf){
#pragma unroll
      for (int i=0;i<4;++i){
        const float iv = fsig (acc[0+hf][i]);
        const float fv = fsig (acc[2+hf][i]);
        const float gv = ftanh(acc[4+hf][i]);
        const float ov = fsig (acc[6+hf][i]);
        const float cc = fv*c[hf][i] + iv*gv;
        c[hf][i] = cc;
        const float hh = ov*ftanh(cc);
        const u16 hb = f2b(hh);
        *(u16*)(hwr + (size_t)(4*g4+i)*528 + 2*(32*w + 16*hf + l15)) = hb;
        yp[(size_t)i*256 + hf*16] = hb;
      }
    }
    yp += 65536;
    __syncthreads();
  }

  // final state write-back (nsteps even -> last h in smH0)
#pragma unroll
  for (int hf=0; hf<2; ++hf)
#pragma unroll
    for (int i=0;i<4;++i){
      const int b  = 4*g4 + i;
      const int jh = 32*w + 16*hf + l15;
      hout[(size_t)(b0+b)*256 + jh] = b2f(*(u16*)(smH0 + (size_t)b*528 + 2*jh));
      cout[(size_t)(b0+b)*256 + jh] = c[hf][i];
    }
}

// ---------------------------------------------------------------------------
// Mega dispatch d — ALL work is cross-dispatch independent (kernel-boundary
// coherence only; zero atomics/fences, per Guideline 16):
//   blocks 0-15 : R0(d)    layer-0 rec chunk d
//   blocks 16-31: R1(d-2)  layer-1 rec chunk d-2
//   blocks 32+  : chasers: G0(d+1), G1(d-1), FC(d-3)
// Grid 256 x 512thr, LDS 148K -> 1 block/CU.
// ---------------------------------------------------------------------------
__global__ __launch_bounds__(512,2) void mega(
    int hasR0, int hasR1, int hasG0, int hasG1, int hasFC, int nsteps,
    const u16* __restrict__ xg0r, const float* hinA, const float* cinA,
    u16* y0wr, float* houtA, float* coutA,
    const u16* __restrict__ xg1r, const float* hinB, const float* cinB,
    u16* y1wr, float* houtB, float* coutB,
    const float* __restrict__ xG0, u16* __restrict__ xg0w,
    const u16* __restrict__ y0rd, u16* __restrict__ xg1w,
    const u16* __restrict__ y1fc, float* __restrict__ outfc,
    const u16* __restrict__ wih0p, const float* __restrict__ bias0,
    const u16* __restrict__ wih1p, const float* __restrict__ bias1,
    const u16* __restrict__ whh0p, const u16* __restrict__ whh1p,
    const u16* __restrict__ wfcp,  const float* __restrict__ bfc)
{
  __shared__ char smem[147968];
  const int bid = (int)blockIdx.x;
  const int ntG = nsteps * 16;

  if (bid < 16){
    if (hasR0)
      rec_body(smem, smem+131072, smem+131072+8448, xg0r, whh0p,
               hinA, cinA, y0wr, houtA, coutA, bid, nsteps);
  } else if (bid < 32){
    if (hasR1)
      rec_body(smem, smem+131072, smem+131072+8448, xg1r, whh1p,
               hinB, cinB, y1wr, houtB, coutB, bid-16, nsteps);
  } else {
    const int gb = bid - 32;   // 0..223
    if (hasG0){
      for (int tile = gb; tile < ntG; tile += 224){
        gemm_body<4,true >(smem, xG0, wih0p, bias0, xg0w, VV, tile&3, tile>>2);
        __syncthreads();
      }
    }
    if (hasG1){
      for (int tile = gb; tile < ntG; tile += 224){
        gemm_body<8,false>(smem, y0rd, wih1p, bias1, xg1w, HH, tile&3, tile>>2);
        __syncthreads();
      }
    }
    if (hasFC){
      for (int tile = gb; tile < nsteps*4; tile += 224){
        fc_body(smem, y1fc, wfcp, bfc, outfc, tile);
        __syncthreads();
      }
    }
  }
}

// ---------------------------------------------------------------------------
extern "C" void kernel_launch(void* const* d_in, const int* in_sizes, int n_in,
                              void* d_out, int out_size, void* d_ws, size_t ws_size,
                              hipStream_t stream) {
  (void)in_sizes; (void)n_in; (void)out_size;
  const float* x    = (const float*)d_in[0];
  const float* h0   = (const float*)d_in[1];
  const float* c0   = (const float*)d_in[2];
  const float* Wih0 = (const float*)d_in[3];
  const float* Whh0 = (const float*)d_in[4];
  const float* bih0 = (const float*)d_in[5];
  const float* bhh0 = (const float*)d_in[6];
  const float* Wih1 = (const float*)d_in[7];
  const float* Whh1 = (const float*)d_in[8];
  const float* bih1 = (const float*)d_in[9];
  const float* bhh1 = (const float*)d_in[10];
  const float* Wfc  = (const float*)d_in[11];
  const float* bfc  = (const float*)d_in[12];
  float* out = (float*)d_out;

  // runtime chunk: TC=32 (~81MB ws) if available, else TC=16 (~44MB, proven)
  const int TCr  = (ws_size >= (size_t)82*1024*1024) ? 32 : 16;
  const int NCHr = TT / TCr;
  const size_t XGB = (size_t)TCr*BB*1024*2 + 524288;  // bytes/xg buf (+slack)
  const size_t Y0B = (size_t)TCr*BB*HH*2;

  char* p = (char*)d_ws;
  u16* xg0b[2]; u16* xg1b[2]; u16* y0b[2];
  xg0b[0] = (u16*)p; p += XGB;
  xg0b[1] = (u16*)p; p += XGB;
  xg1b[0] = (u16*)p; p += XGB;
  xg1b[1] = (u16*)p; p += XGB;
  y0b[0]  = (u16*)p; p += Y0B;
  y0b[1]  = (u16*)p; p += Y0B;
  u16* whh0p = (u16*)p; p += 524288;
  u16* whh1p = (u16*)p; p += 524288;
  u16* wih0p = (u16*)p; p += 262144;
  u16* wih1p = (u16*)p; p += 524288;
  u16* wfcp  = (u16*)p; p += 65536;
  float* bias0 = (float*)p; p += 4096;
  float* bias1 = (float*)p; p += 4096;
  float* hst0 = (float*)p; p += 262144;
  float* cst0 = (float*)p; p += 262144;
  float* hst1 = (float*)p; p += 262144;
  float* cst1 = (float*)p; p += 262144;

  u16* y1    = (u16*)d_out;          // bf16 y1 aliases out rows; FC rewrites
  float* hid = out + 16777216;       // them in-place 3 dispatches later
  float* cel = hid + 131072;

  pack_b<<<64 ,256,0,stream>>>(Wih0, wih0p, 1024,128);
  pack_b<<<128,256,0,stream>>>(Whh0, whh0p, 1024,256);
  pack_b<<<128,256,0,stream>>>(Wih1, wih1p, 1024,256);
  pack_b<<<128,256,0,stream>>>(Whh1, whh1p, 1024,256);
  pack_b<<<16 ,256,0,stream>>>(Wfc,  wfcp,  128,256);
  bias_sum<<<8,256,0,stream>>>(bih0,bhh0,bias0, bih1,bhh1,bias1);

  // prologue: G0(0)
  gemm_perm0<<<dim3(4, TCr*4),512,0,stream>>>(x, wih0p, bias0, xg0b[0]);

  for (int d = 0; d <= NCHr + 2; ++d){
    const int hasR0 = (d < NCHr);
    const int hasR1 = (d >= 2) && (d < NCHr + 2);
    const int hasG0 = (d + 1 < NCHr);
    const int hasG1 = (d >= 1) && (d - 1 < NCHr);
    const int hasFC = (d >= 3) && (d - 3 < NCHr);
    const int cR1 = hasR1 ? d-2 : 0;
    const int cG0 = hasG0 ? d+1 : 0;
    const int cFC = hasFC ? d-3 : 0;
    mega<<<256,512,0,stream>>>(
      hasR0, hasR1, hasG0, hasG1, hasFC, TCr,
      // R0(d)
      xg0b[d&1],
      (d==0) ? h0 : hst0, (d==0) ? c0 : cst0,
      y0b[d&1],
      (d==NCHr-1) ? hid : hst0, (d==NCHr-1) ? cel : cst0,
      // R1(d-2)
      xg1b[d&1],
      (cR1==0) ? (h0+65536) : hst1, (cR1==0) ? (c0+65536) : cst1,
      y1 + (size_t)cR1*TCr*BB*HH,
      (cR1==NCHr-1) ? (hid+65536) : hst1, (cR1==NCHr-1) ? (cel+65536) : cst1,
      // G0(d+1)
      x + (size_t)cG0*TCr*BB*VV, xg0b[(d+1)&1],
      // G1(d-1): reads y0(d-1), writes xg1(d-1)
      y0b[(d-1)&1], xg1b[(d-1)&1],
      // FC(d-3)
      y1 + (size_t)cFC*TCr*BB*HH, out + (size_t)cFC*TCr*BB*VV,
      wih0p, bias0, wih1p, bias1, whh0p, whh1p, wfcp, bfc);
  }
}